// Round 8
// baseline (574.960 us; speedup 1.0000x reference)
//
#include <hip/hip_runtime.h>

// DiffTreeInterpreter: token-centric atomic-scatter edition.
//
// R0-R7 established (counter-verified):
//  - output-centric gather is service-rate-bound on its random-512B pattern
//    (~2.1 TB/s; MLP=20 proven in flight in R6 changed nothing; FETCH already
//    at compulsory floor per R7's unchanged FETCH under NT policy).
//  - Same bytes STREAMED run ~3x faster on this chip (6.3 TB/s, m13).
// R8: invert the dataflow. Stream mem_values sequentially (one wave = 4
// consecutive rows), and atomicAdd the <=3 scaled copies of each row into out:
//   half: row (b, rr>>1)        scale op0*w0 (rr even) / op1*w1 (rr odd>=3)
//   cons: rows (b,2rr),(b,2rr+1) scales op2*w2 / op2*w3   (rr < 2048)
//   root: out[b,1,:] += op2*root_filler[b]  (folded into init kernel)
// Eliminates: build_kernel, 25MB record structure, ovf pass, ws memset.
// Pad rows (n < N/20) are all-zero by construction -> contributions are
// exact zeros -> skipped (same property prior rounds relied on).
// Out is zero+root-initialized by init_kernel with NORMAL stores so the lines
// sit dirty in LLC when the atomics RMW them.
// Unknown being tested: MALL/LLC atomic f32 RMW service rate. Gate: scatter
// >= 100us means atomics are the wall -> revert to R7 structure.

namespace {
constexpr int kB = 32;
constexpr int kF = 128;
constexpr int kR = 4096;
constexpr int kN = 262144;
constexpr int kQ = 2048;        // interior roles for cons
constexpr int kPad = kN / 20;   // 13107: mem rows [0,kPad) are all-zero
}  // namespace

// out = (B, R, F) f32 = 32*4096*128 = 16,777,216 f32 = 4,194,304 float4.
// Zeros everywhere except row r==1: op2[b] * root_filler[b].
__global__ __launch_bounds__(256) void init_kernel(
    const float4* __restrict__ root4, const float* __restrict__ opd,
    float4* __restrict__ out4) {
  const int idx = blockIdx.x * 256 + threadIdx.x;  // 16384 blocks cover exactly
  const int row = idx >> 5;                        // 32 float4 per row
  const int r = row & (kR - 1);
  float4 v = make_float4(0.f, 0.f, 0.f, 0.f);
  if (r == 1) {
    const int b = row >> 12;
    const float op2 = opd[3 * b + 2];
    const float4 rf = root4[(b << 5) | (idx & 31)];
    v = make_float4(op2 * rf.x, op2 * rf.y, op2 * rf.z, op2 * rf.w);
  }
  out4[idx] = v;  // normal store: allocate in LLC for the atomics to hit
}

// One wave handles 4 consecutive tokens (rows n0..n0+3): mem read is a pure
// 2KB-contiguous stream per wave; destinations are the random side, handled
// by fire-and-forget f32 atomics (device scope = MALL coherence point).
__global__ __launch_bounds__(256) void scatter_kernel(
    const float2* __restrict__ mem2, const float4* __restrict__ aw4,
    const float* __restrict__ opd, const int* __restrict__ bidx,
    const int* __restrict__ sidx, const int* __restrict__ ridx,
    float* __restrict__ out) {
  const int wv = blockIdx.x * 4 + (threadIdx.x >> 6);  // wave id
  const int t = threadIdx.x & 63;                      // features 2t, 2t+1
  const int n0 = wv << 2;                              // first of 4 tokens

  // token metadata: three 16B broadcast loads
  const int4 b4 = *(const int4*)(bidx + n0);
  const int4 s4 = *(const int4*)(sidx + n0);
  const int4 r4 = *(const int4*)(ridx + n0);

  // 4 streaming row loads, issued together
  float2 m[4];
#pragma unroll
  for (int j = 0; j < 4; ++j) m[j] = mem2[((size_t)(n0 + j) << 6) + t];

#pragma unroll
  for (int j = 0; j < 4; ++j) {
    if (n0 + j < kPad) continue;  // all-zero row: contributions are exact 0
    const int b = j == 0 ? b4.x : j == 1 ? b4.y : j == 2 ? b4.z : b4.w;
    const int s = j == 0 ? s4.x : j == 1 ? s4.y : j == 2 ? s4.z : s4.w;
    const int rr = j == 0 ? r4.x : j == 1 ? r4.y : j == 2 ? r4.z : r4.w;
    const float4 w = aw4[(b << 7) | s];
    const bool even = (rr & 1) == 0;

    // half contribution -> row rr>>1 (car if even, cdr if odd>=3; role 1 drop)
    if (even || rr >= 3) {
      const float sc = even ? opd[3 * b] * w.x : opd[3 * b + 1] * w.y;
      float* dst = out + (((size_t)((b << 12) | (rr >> 1))) << 7) + 2 * t;
      atomicAdd(dst, sc * m[j].x);
      atomicAdd(dst + 1, sc * m[j].y);
    }
    // cons contribution -> rows 2rr, 2rr+1
    if (rr < kQ) {
      const float op2 = opd[3 * b + 2];
      const float s1 = op2 * w.z;
      const float s2 = op2 * w.w;
      float* dst = out + (((size_t)((b << 12) | (rr << 1))) << 7) + 2 * t;
      atomicAdd(dst, s1 * m[j].x);
      atomicAdd(dst + 1, s1 * m[j].y);
      atomicAdd(dst + kF, s2 * m[j].x);
      atomicAdd(dst + kF + 1, s2 * m[j].y);
    }
  }
}

extern "C" void kernel_launch(void* const* d_in, const int* in_sizes, int n_in,
                              void* d_out, int out_size, void* d_ws, size_t ws_size,
                              hipStream_t stream) {
  const float* mem   = (const float*)d_in[0];   // (N, F)
  const float* aw    = (const float*)d_in[1];   // (B, L, 4)
  const float* rootf = (const float*)d_in[2];   // (B, F)
  const float* opd   = (const float*)d_in[3];   // (B, 3)
  const int* bidx    = (const int*)d_in[4];     // (N,)
  const int* sidx    = (const int*)d_in[5];     // (N,)
  const int* ridx    = (const int*)d_in[6];     // (N,)
  (void)d_ws; (void)ws_size;  // workspace unused: no records, no counters

  // out init: 4,194,304 float4 / 256 threads = 16384 blocks
  init_kernel<<<16384, 256, 0, stream>>>((const float4*)rootf, opd,
                                         (float4*)d_out);

  // 16 tokens per 256-thread block (4 waves x 4 tokens) -> 16384 blocks
  scatter_kernel<<<kN / 16, 256, 0, stream>>>(
      (const float2*)mem, (const float4*)aw, opd, bidx, sidx, ridx,
      (float*)d_out);
}

// Round 9
// 264.800 us; speedup vs baseline: 2.1713x; 2.1713x over previous
//
#include <hip/hip_runtime.h>

// DiffTreeInterpreter: row-pair CSR gather, R7 structure + guarded asm-batch
// loads (clean MLP test).
//
// Output row r (batch b):
//   half: r<2048: car from role 2r (scale op0*w0), cdr from role 2r+1>=3 (op1*w1)
//   cons: all r: from role r>>1 (scale op2*w2 if r even else op2*w3)
//   root: out[b,1,:] += op2*root_filler[b]
//
// History (counter-verified):
//  R1/R2 TLP variants: regressed. R3/R4/R5 scheduler hints: no-ops (VGPR=48).
//  R6 unconditional asm batch: MLP=20 in flight but +65% dummy loads -> +25us
//     (confounded A/B). R7 NT stores: -4us (kept). R8 atomic scatter: 408us,
//     WRITE_SIZE 498MB -> atomics write through to HBM, dead end.
//  ~165us of dur_us is fixed harness overhead (R8 cross-check); gather is the
//  only lever.
// R9: R7's exact kernel with the asm load batches INSIDE the wave-uniform
// guards -- dummy volume identical to R7, back-to-back issue + single drain
// guaranteed at ISA level. This is the clean test of "does per-wave MLP help
// the random-512B pattern at all". If neutral: service-rate wall confirmed,
// R7 is the floor.

namespace {
constexpr int kB = 32;
constexpr int kL = 128;
constexpr int kF = 128;
constexpr int kR = 4096;
constexpr int kN = 262144;
constexpr int kQ = 2048;       // row-pairs per batch == half-rows per batch
constexpr int kNP = kB * kQ;   // 65536 keys
constexpr int kCap = 16;       // entries per record; P(Poisson(4)>16)~4e-7
constexpr int kOvfMax = 65536;

// workspace layout (bytes)
constexpr size_t kOffRowCnt  = 0;        // kNP*4  = 262144
constexpr size_t kOffConsCnt = 262144;   // kNP*4  = 262144
constexpr size_t kOffOvfCnt  = 524288;   // 4 (pad 16)
constexpr size_t kOffOvf     = 524304;   // kOvfMax*16 = 1048576
constexpr size_t kOffRowEnt  = 1572880;  // kNP*kCap*8  = 8388608  (int2)
constexpr size_t kOffConsEnt = 9961488;  // kNP*kCap*16 = 16777216 (int4)
// end: 26,738,704 bytes (~25.5 MB)
}  // namespace

typedef int   __attribute__((ext_vector_type(2))) i32x2;
typedef float __attribute__((ext_vector_type(2))) f32x2;

__global__ __launch_bounds__(256) void build_kernel(
    const float4* __restrict__ aw, const float* __restrict__ opd,
    const int* __restrict__ bidx, const int* __restrict__ sidx,
    const int* __restrict__ ridx,
    int* __restrict__ rowcnt, int* __restrict__ conscnt,
    int* __restrict__ ovf_cnt, int4* __restrict__ ovf,
    int2* __restrict__ rowent, int4* __restrict__ consent) {
  int n = blockIdx.x * 256 + threadIdx.x;
  if (n >= kN) return;
  int b = bidx[n];
  int s = sidx[n];
  int rr = ridx[n];
  float4 w = aw[b * kL + s];
  float op0 = opd[3 * b + 0];
  float op1 = opd[3 * b + 1];
  float op2 = opd[3 * b + 2];

  // half contribution -> row rr>>1 (car if even, cdr if odd>=3; role 1 dropped)
  bool even = (rr & 1) == 0;
  if (even || rr >= 3) {
    float sc = even ? op0 * w.x : op1 * w.y;
    int key = (b << 11) | (rr >> 1);
    int pos = atomicAdd(&rowcnt[key], 1);
    if (pos < kCap) {
      rowent[key * kCap + pos] = make_int2(n, __float_as_int(sc));
    } else {
      int o = atomicAdd(ovf_cnt, 1);
      if (o < kOvfMax)
        ovf[o] = make_int4(b * kR + (rr >> 1), n, __float_as_int(sc), 0);
    }
  }
  // cons contribution -> rows 2rr, 2rr+1 : ONE entry (n, s1, s2)
  if (rr < kQ) {
    int key = (b << 11) | rr;
    int pos = atomicAdd(&conscnt[key], 1);
    if (pos < kCap) {
      consent[key * kCap + pos] =
          make_int4(n, __float_as_int(op2 * w.z), __float_as_int(op2 * w.w), 0);
    } else {
      int o = atomicAdd(ovf_cnt, 2);
      if (o < kOvfMax)
        ovf[o] = make_int4(b * kR + 2 * rr, n, __float_as_int(op2 * w.z), 0);
      if (o + 1 < kOvfMax)
        ovf[o + 1] =
            make_int4(b * kR + 2 * rr + 1, n, __float_as_int(op2 * w.w), 0);
    }
  }
}

// Inline-asm 8B load: volatile => ordered with other asm, never re-scheduled,
// no compiler-inserted waitcnt (we drain manually, once).
#define GLOAD(dst, a64) \
  asm volatile("global_load_dwordx2 %0, %1, off" : "=v"(dst) : "v"(a64))

__global__ __launch_bounds__(256) void gather_kernel(
    const float2* __restrict__ mem2, const float2* __restrict__ root2,
    const float* __restrict__ opd,
    const int* __restrict__ rowcnt, const int* __restrict__ conscnt,
    const int2* __restrict__ rowent, const int2* __restrict__ consent2,
    float2* __restrict__ out2) {
  const int p = blockIdx.x * 4 + (threadIdx.x >> 6);  // pair id = (b<<11)|q
  const int t = threadIdx.x & 63;                     // lane: features 2t,2t+1
  const int b = p >> 11;
  const int q = p & (kQ - 1);
  const bool hashalf = q < 1024;  // rows 2q,2q+1 < 2048

  // ---- round 1: ALL structure loads, fully independent (NT: read-once) ----
  int cn_raw = __builtin_nontemporal_load(conscnt + p);
  i32x2 ce = (i32x2)0;
  if (t < 32)
    ce = __builtin_nontemporal_load(
        (const i32x2*)(consent2 + (size_t)p * 2 * kCap) + t);
  i32x2 hc = (i32x2)0;
  i32x2 he = (i32x2)0;
  if (hashalf) {
    int key0 = (b << 11) | (q << 1);  // even -> 8B aligned
    hc = __builtin_nontemporal_load((const i32x2*)(rowcnt + key0));
    if (t < 32)
      he = __builtin_nontemporal_load(
          (const i32x2*)(rowent + (size_t)key0 * kCap) + t);
  }
  int cn = min(__builtin_amdgcn_readfirstlane(cn_raw), kCap);
  int h0 = 0, h1 = 0;
  if (hashalf) {
    h0 = min(__builtin_amdgcn_readfirstlane(hc.x), kCap);
    h1 = min(__builtin_amdgcn_readfirstlane(hc.y), kCap);
  }

  // ---- round 2: issue phase -- guarded asm batches (same dummy volume as
  // R7's compiler version; issue order and single drain now ISA-guaranteed).
  const uint64_t membase = (uint64_t)(const void*)mem2 + (uint64_t)(t << 3);

  f32x2 mc[4], m0[8], m1[8];
  float c1s[4], c2s[4], s0a[8], s1a[8];
#pragma unroll
  for (int j = 0; j < 4; ++j) {
    c1s[j] = 0.f;
    c2s[j] = 0.f;
    mc[j] = (f32x2)0.f;
  }
#pragma unroll
  for (int j = 0; j < 8; ++j) {
    s0a[j] = 0.f;
    s1a[j] = 0.f;
    m0[j] = (f32x2)0.f;
    m1[j] = (f32x2)0.f;
  }
  if (cn > 0) {
#pragma unroll
    for (int j = 0; j < 4; ++j) {
      bool v = j < cn;
      int nn = __shfl(ce.x, 2 * j);
      float a = __int_as_float(__shfl(ce.y, 2 * j));
      float bb = __int_as_float(__shfl(ce.x, 2 * j + 1));
      nn = v ? nn : 0;  // slots >= cn hold 0xAA poison
      c1s[j] = v ? a : 0.f;
      c2s[j] = v ? bb : 0.f;
      GLOAD(mc[j], membase + ((uint64_t)(uint32_t)nn << 9));
    }
  }
  if (h0 > 0) {
#pragma unroll
    for (int j = 0; j < 4; ++j) {
      bool v = j < h0;
      int nn = __shfl(he.x, j);
      float s = __int_as_float(__shfl(he.y, j));
      nn = v ? nn : 0;
      s0a[j] = v ? s : 0.f;
      GLOAD(m0[j], membase + ((uint64_t)(uint32_t)nn << 9));
    }
    if (h0 > 4) {
#pragma unroll
      for (int j = 4; j < 8; ++j) {
        bool v = j < h0;
        int nn = __shfl(he.x, j);
        float s = __int_as_float(__shfl(he.y, j));
        nn = v ? nn : 0;
        s0a[j] = v ? s : 0.f;
        GLOAD(m0[j], membase + ((uint64_t)(uint32_t)nn << 9));
      }
    }
  }
  if (h1 > 0) {
#pragma unroll
    for (int j = 0; j < 4; ++j) {
      bool v = j < h1;
      int nn = __shfl(he.x, 16 + j);
      float s = __int_as_float(__shfl(he.y, 16 + j));
      nn = v ? nn : 0;
      s1a[j] = v ? s : 0.f;
      GLOAD(m1[j], membase + ((uint64_t)(uint32_t)nn << 9));
    }
    if (h1 > 4) {
#pragma unroll
      for (int j = 4; j < 8; ++j) {
        bool v = j < h1;
        int nn = __shfl(he.x, 16 + j);
        float s = __int_as_float(__shfl(he.y, 16 + j));
        nn = v ? nn : 0;
        s1a[j] = v ? s : 0.f;
        GLOAD(m1[j], membase + ((uint64_t)(uint32_t)nn << 9));
      }
    }
  }

  // ---- ONE drain; "+v" on every destination makes all consumers
  // data-dependent on the post-wait values.
  asm volatile("s_waitcnt vmcnt(0)"
               : "+v"(mc[0]), "+v"(mc[1]), "+v"(mc[2]), "+v"(mc[3]),
                 "+v"(m0[0]), "+v"(m0[1]), "+v"(m0[2]), "+v"(m0[3]),
                 "+v"(m0[4]), "+v"(m0[5]), "+v"(m0[6]), "+v"(m0[7]),
                 "+v"(m1[0]), "+v"(m1[1]), "+v"(m1[2]), "+v"(m1[3]),
                 "+v"(m1[4]), "+v"(m1[5]), "+v"(m1[6]), "+v"(m1[7])
               :
               : "memory");
  __builtin_amdgcn_sched_barrier(0);  // rule #18

  // ---- accumulate ----
  float ax0 = 0.f, ay0 = 0.f, ax1 = 0.f, ay1 = 0.f;
#pragma unroll
  for (int j = 0; j < 4; ++j) {
    ax0 += c1s[j] * mc[j][0];
    ay0 += c1s[j] * mc[j][1];
    ax1 += c2s[j] * mc[j][0];
    ay1 += c2s[j] * mc[j][1];
  }
#pragma unroll
  for (int j = 0; j < 8; ++j) {
    ax0 += s0a[j] * m0[j][0];
    ay0 += s0a[j] * m0[j][1];
  }
#pragma unroll
  for (int j = 0; j < 8; ++j) {
    ax1 += s1a[j] * m1[j][0];
    ay1 += s1a[j] * m1[j][1];
  }

  // ---- rare tails (drained region; compiler loads) ----
  for (int i = 4; i < cn; i += 4) {
#pragma unroll
    for (int j = 0; j < 4; ++j) {
      int idx = i + j;
      bool v = idx < cn;
      int nn = __shfl(ce.x, 2 * idx);
      float a = __int_as_float(__shfl(ce.y, 2 * idx));
      float bb = __int_as_float(__shfl(ce.x, 2 * idx + 1));
      nn = v ? nn : 0;
      a = v ? a : 0.f;
      bb = v ? bb : 0.f;
      float2 m = mem2[(size_t)nn * (kF / 2) + t];
      ax0 += a * m.x;
      ay0 += a * m.y;
      ax1 += bb * m.x;
      ay1 += bb * m.y;
    }
  }
  for (int i = 8; i < h0; i += 4) {
#pragma unroll
    for (int j = 0; j < 4; ++j) {
      int idx = i + j;
      bool v = idx < h0;
      int nn = __shfl(he.x, idx);
      float s = __int_as_float(__shfl(he.y, idx));
      nn = v ? nn : 0;
      s = v ? s : 0.f;
      float2 m = mem2[(size_t)nn * (kF / 2) + t];
      ax0 += s * m.x;
      ay0 += s * m.y;
    }
  }
  for (int i = 8; i < h1; i += 4) {
#pragma unroll
    for (int j = 0; j < 4; ++j) {
      int idx = i + j;
      bool v = idx < h1;
      int nn = __shfl(he.x, 16 + idx);
      float s = __int_as_float(__shfl(he.y, 16 + idx));
      nn = v ? nn : 0;
      s = v ? s : 0.f;
      float2 m = mem2[(size_t)nn * (kF / 2) + t];
      ax1 += s * m.x;
      ay1 += s * m.y;
    }
  }

  // ---- root filler (row 1 <=> q==0) + NT writeback (R7 win) ----
  if (q == 0) {
    float op2 = opd[3 * b + 2];
    float2 rf = root2[b * (kF / 2) + t];
    ax1 += op2 * rf.x;
    ay1 += op2 * rf.y;
  }
  size_t orow = ((size_t)b * kR + 2 * q) * (kF / 2) + t;
  f32x2 o0;
  o0.x = ax0;
  o0.y = ay0;
  f32x2 o1;
  o1.x = ax1;
  o1.y = ay1;
  __builtin_nontemporal_store(o0, (f32x2*)(out2 + orow));
  __builtin_nontemporal_store(o1, (f32x2*)(out2 + orow + (kF / 2)));
}

// Overflow fallback (expected ~0 entries): direct atomic add.
// Must run AFTER gather_kernel (gather writes out with '=').
__global__ __launch_bounds__(128) void ovf_kernel(
    const float* __restrict__ mem, const int* __restrict__ ovf_cnt,
    const int4* __restrict__ ovf, float* __restrict__ out) {
  int m = *ovf_cnt;
  if (m > kOvfMax) m = kOvfMax;
  const int t = threadIdx.x;  // feature 0..127
  for (int i = blockIdx.x; i < m; i += gridDim.x) {
    int4 e = ovf[i];
    float sc = __int_as_float(e.z);
    atomicAdd(&out[(size_t)e.x * kF + t], sc * mem[(size_t)e.y * kF + t]);
  }
}

extern "C" void kernel_launch(void* const* d_in, const int* in_sizes, int n_in,
                              void* d_out, int out_size, void* d_ws, size_t ws_size,
                              hipStream_t stream) {
  const float* mem   = (const float*)d_in[0];   // (N, F)
  const float* aw    = (const float*)d_in[1];   // (B, L, 4)
  const float* rootf = (const float*)d_in[2];   // (B, F)
  const float* opd   = (const float*)d_in[3];   // (B, 3)
  const int* bidx    = (const int*)d_in[4];     // (N,)
  const int* sidx    = (const int*)d_in[5];     // (N,)
  const int* ridx    = (const int*)d_in[6];     // (N,)

  char* ws = (char*)d_ws;
  int* rowcnt   = (int*)(ws + kOffRowCnt);
  int* conscnt  = (int*)(ws + kOffConsCnt);
  int* ovf_cnt  = (int*)(ws + kOffOvfCnt);
  int4* ovf     = (int4*)(ws + kOffOvf);
  int2* rowent  = (int2*)(ws + kOffRowEnt);
  int4* consent = (int4*)(ws + kOffConsEnt);

  // zero all counters in one contiguous memset (ws is poisoned 0xAA each call)
  hipMemsetAsync(ws, 0, kOffOvfCnt + 16, stream);

  build_kernel<<<kN / 256, 256, 0, stream>>>(
      (const float4*)aw, opd, bidx, sidx, ridx, rowcnt, conscnt, ovf_cnt, ovf,
      rowent, consent);

  // 4 pairs per 256-thread block (4 waves x 1 pair) -> 16384 blocks.
  gather_kernel<<<kNP / 4, 256, 0, stream>>>(
      (const float2*)mem, (const float2*)rootf, opd, rowcnt, conscnt, rowent,
      (const int2*)consent, (float2*)d_out);

  ovf_kernel<<<64, 128, 0, stream>>>(mem, ovf_cnt, ovf, (float*)d_out);
}